// Round 14
// baseline (119.365 us; speedup 1.0000x reference)
//
#include <hip/hip_runtime.h>

#define N_VOX 32768
#define CCH 128
#define EPSV 1e-5f

typedef __attribute__((ext_vector_type(8))) short bfrag;
typedef __attribute__((ext_vector_type(4))) float ffrag;
typedef __attribute__((ext_vector_type(2))) unsigned int u32x2;

__device__ __forceinline__ unsigned short f2bf(float f) {
    union { float f; unsigned int i; } c; c.f = f;
    unsigned int i = c.i;
    return (unsigned short)((i + 0x7FFFu + ((i >> 16) & 1u)) >> 16);
}
__device__ __forceinline__ unsigned int cvtpk(float lo, float hi) {
    unsigned int r;
    asm("v_cvt_pk_bf16_f32 %0, %1, %2" : "=v"(r) : "v"(lo), "v"(hi));
    return r;
}

// -------- Kernel 0: one-shot fp32 -> bf16 weight conversion --------
__global__ __launch_bounds__(256) void wconv(const float* __restrict__ qkv_w,
                                             const float* __restrict__ proj_w,
                                             unsigned short* __restrict__ wq,
                                             unsigned short* __restrict__ wp) {
    int i = blockIdx.x * 256 + threadIdx.x;
    if (i < 12288) {
        float4 v = ((const float4*)qkv_w)[i];
        u32x2 o; o.x = cvtpk(v.x, v.y); o.y = cvtpk(v.z, v.w);
        *(u32x2*)&wq[i * 4] = o;
    } else {
        int j = i - 12288;
        float4 v = ((const float4*)proj_w)[j];
        u32x2 o; o.x = cvtpk(v.x, v.y); o.y = cvtpk(v.z, v.w);
        *(u32x2*)&wp[j * 4] = o;
    }
}

// -------- Kernel 1: fused LayerNorm + QKV GEMM (og=1, verified round-11) --------
__global__ __launch_bounds__(256) void ln_qkv(const float* __restrict__ x,
                                              const float* __restrict__ gamma,
                                              const float* __restrict__ beta,
                                              const unsigned short* __restrict__ wq,
                                              const float* __restrict__ bias,
                                              unsigned short* __restrict__ qkv) {
    __shared__ __align__(16) unsigned short a_s[64 * 136];
    __shared__ __align__(16) unsigned short b_s[64 * 136];
    __shared__ float ps[256], pq[256];
    __shared__ float muS[64], rsS[64];
    __shared__ float g[128], bta[128];
    int t = threadIdx.x;
    int v0 = blockIdx.x * 64;
    if (t < 128) { g[t] = gamma[t]; bta[t] = beta[t]; }
    int cq = t >> 6, v = t & 63;
    float xr[32];
    float s = 0.f, sq = 0.f;
    #pragma unroll
    for (int i = 0; i < 32; i++) {
        float val = x[(size_t)(cq * 32 + i) * N_VOX + v0 + v];
        xr[i] = val; s += val; sq += val * val;
    }
    ps[t] = s; pq[t] = sq;
    __syncthreads();
    if (t < 64) {
        float S = ps[t] + ps[t + 64] + ps[t + 128] + ps[t + 192];
        float Q = pq[t] + pq[t + 64] + pq[t + 128] + pq[t + 192];
        float mu = S * (1.0f / 128.0f);
        float var = Q * (1.0f / 128.0f) - mu * mu;
        muS[t] = mu; rsS[t] = rsqrtf(var + EPSV);
    }
    __syncthreads();
    {
        float mu = muS[v], rs = rsS[v];
        #pragma unroll
        for (int i8 = 0; i8 < 4; i8++) {
            float val[8];
            #pragma unroll
            for (int k = 0; k < 8; k++) {
                int c = cq * 32 + i8 * 8 + k;
                val[k] = (xr[i8 * 8 + k] - mu) * rs * g[c] + bta[c];
            }
            uint4 q;
            q.x = cvtpk(val[0], val[1]);
            q.y = cvtpk(val[2], val[3]);
            q.z = cvtpk(val[4], val[5]);
            q.w = cvtpk(val[6], val[7]);
            *(uint4*)&a_s[v * 136 + cq * 32 + i8 * 8] = q;
        }
    }
    __syncthreads();
    int lane = t & 63, wvi = t >> 6, m = lane & 15, quad = lane >> 4;
    bfrag areg[4];
    #pragma unroll
    for (int kk = 0; kk < 4; kk++)
        areg[kk] = *(bfrag*)&a_s[(wvi * 16 + m) * 136 + kk * 32 + quad * 8];
    for (int t0 = 0; t0 < 6; t0++) {
        int o0 = t0 * 64;
        {
            int r4 = t >> 4, c8 = t & 15;
            #pragma unroll
            for (int pass = 0; pass < 4; pass++) {
                int r = pass * 16 + r4;
                *(uint4*)&b_s[r * 136 + c8 * 8] =
                    *(const uint4*)&wq[(size_t)(o0 + r) * 128 + c8 * 8];
            }
        }
        __syncthreads();
        ffrag acc[4] = {ffrag{0,0,0,0}, ffrag{0,0,0,0}, ffrag{0,0,0,0}, ffrag{0,0,0,0}};
        #pragma unroll
        for (int kk = 0; kk < 4; kk++) {
            #pragma unroll
            for (int nt = 0; nt < 4; nt++) {
                bfrag bb = *(bfrag*)&b_s[(nt * 16 + m) * 136 + kk * 32 + quad * 8];
                acc[nt] = __builtin_amdgcn_mfma_f32_16x16x32_bf16(areg[kk], bb, acc[nt], 0, 0, 0);
            }
        }
        bool isq = (o0 < 128);
        #pragma unroll
        for (int nt = 0; nt < 4; nt++) {
            int o = o0 + nt * 16 + m;
            float bs = bias[o];
            int sec = o >> 7;
            int oc = o & 127;
            unsigned short* dst = qkv + (size_t)sec * ((size_t)N_VOX * 128);
            #pragma unroll
            for (int r = 0; r < 4; r++) {
                int vg = v0 + wvi * 16 + quad * 4 + r;
                float val = acc[nt][r] + bs;
                if (isq) val *= 0.17677669529663687f;
                dst[(size_t)vg * 128 + oc] = f2bf(val);
            }
        }
        __syncthreads();
    }
}

// -------- Kernel 2: neighborhood attention, 2x2x4 cubes, NO V LDS staging --------
// V was staged through 25.6KB of LDS purely as a TRANSPOSE (each byte written
// once, read once). Instead each lane loads its PV A-fragment elements
// directly from global: element e of fragment f is
// V[vjtab[f*16+4*hq+e]][ch0(+16)+m] — 32B-contiguous across the 16 lanes of
// an hq group. Two batches of 24 ushort loads (f=0..2 before softmax,
// f=3..5 before PV) so latencies hide under softmax VALU / PV MFMAs.
// Removes 44 v_perm + 12 ds_write + 12 ds_read per lane; LDS -> 0.8KB.
__global__ __launch_bounds__(256) void attn_kernel(const unsigned short* __restrict__ qb,
                                                   const unsigned short* __restrict__ kb,
                                                   const unsigned short* __restrict__ vb,
                                                   unsigned short* __restrict__ ob) {
    __shared__ unsigned int vjtab[96];                    // region idx -> voxel idx
    __shared__ __align__(16) unsigned int vmsk[96];       // region idx -> 16-bit voxel validity

    int t = threadIdx.x;
    int hw = blockIdx.x;
    int bidx = (hw & 7) * 256 + (hw >> 3);                // XCD swizzle
    int czi = bidx & 7, cyi = (bidx >> 3) & 15, cxi = bidx >> 7;
    int cx0 = cxi << 1, cy0 = cyi << 1, cz0 = czi << 2;
    int rx0 = min(max(cx0 - 1, 0), 28);
    int ry0 = min(max(cy0 - 1, 0), 28);
    int rz0 = min(max(cz0 - 1, 0), 26);

    if (t < 96) {
        int r = t;
        int ax = r / 24;
        int rem = r - ax * 24;
        int by = rem / 6;
        int cz = rem - by * 6;
        vjtab[t] = (unsigned)(((rx0 + ax) << 10) + ((ry0 + by) << 5) + (rz0 + cz));
        int wx0 = min(max(cx0 - 1, 0), 29) - rx0;
        int wx1 = min(cx0, 29) - rx0;
        int wy0 = min(max(cy0 - 1, 0), 29) - ry0;
        int wy1 = min(cy0, 29) - ry0;
        unsigned zn = 0;
        #pragma unroll
        for (int vz = 0; vz < 4; vz++) {
            int wz = min(max(cz0 + vz - 1, 0), 29) - rz0;
            if ((unsigned)(cz - wz) <= 2u) zn |= 1u << vz;
        }
        bool x0 = (unsigned)(ax - wx0) <= 2u;
        bool x1 = (unsigned)(ax - wx1) <= 2u;
        bool y0 = (unsigned)(by - wy0) <= 2u;
        bool y1 = (unsigned)(by - wy1) <= 2u;
        unsigned msk = 0;
        if (x0 && y0) msk |= zn;
        if (x0 && y1) msk |= zn << 4;
        if (x1 && y0) msk |= zn << 8;
        if (x1 && y1) msk |= zn << 12;
        vmsk[t] = msk;
    }
    __syncthreads();

    int wave = t >> 6, lane = t & 63;
    int hq = lane >> 4;
    int m = lane & 15;
    int ch0 = wave * 32;

    int gx = cx0 + (m >> 3), gy = cy0 + ((m >> 2) & 1), gz = cz0 + (m & 3);
    int vox = (gx << 10) + (gy << 5) + gz;

    // ---- QK^T (swapped): S^T[r][v], Q pre-scaled ----
    bfrag qf = *(const bfrag*)&qb[(size_t)vox * 128 + ch0 + hq * 8];
    ffrag s[6];
    #pragma unroll
    for (int f = 0; f < 6; f++) {
        unsigned int vj = vjtab[f * 16 + m];
        bfrag kf = *(const bfrag*)&kb[(size_t)vj * 128 + ch0 + hq * 8];
        s[f] = __builtin_amdgcn_mfma_f32_16x16x32_bf16(kf, qf, ffrag{0,0,0,0}, 0, 0, 0);
    }

    // ---- V batch 1 (fragments f=0..2): latency hides under softmax ----
    unsigned short vA0[3][4], vB0[3][4];
    #pragma unroll
    for (int f = 0; f < 3; f++) {
        #pragma unroll
        for (int e = 0; e < 4; e++) {
            unsigned int vj = vjtab[f * 16 + hq * 4 + e];
            const unsigned short* vp = &vb[(size_t)vj * 128 + ch0 + m];
            vA0[f][e] = vp[0];
            vB0[f][e] = vp[16];
        }
    }

    // ---- mask via table + softmax ----
    float mx = -1e30f;
    #pragma unroll
    for (int f = 0; f < 6; f++) {
        uint4 mk = *(const uint4*)&vmsk[f * 16 + hq * 4];
        unsigned mm[4] = {mk.x, mk.y, mk.z, mk.w};
        #pragma unroll
        for (int i = 0; i < 4; i++) {
            bool valid = (mm[i] >> m) & 1u;
            float sv = valid ? s[f][i] : -1e30f;
            s[f][i] = sv;
            mx = fmaxf(mx, sv);
        }
    }
    mx = fmaxf(mx, __shfl_xor(mx, 16));
    mx = fmaxf(mx, __shfl_xor(mx, 32));
    float sum = 0.f;
    #pragma unroll
    for (int f = 0; f < 6; f++) {
        #pragma unroll
        for (int i = 0; i < 4; i++) {
            float p = __expf(s[f][i] - mx);
            s[f][i] = p;
            sum += p;
        }
    }
    sum += __shfl_xor(sum, 16);
    sum += __shfl_xor(sum, 32);
    float inv = 1.0f / sum;

    // ---- V batch 2 (fragments f=3..5): latency hides under PV of batch 1 ----
    unsigned short vA1[3][4], vB1[3][4];
    #pragma unroll
    for (int f = 0; f < 3; f++) {
        #pragma unroll
        for (int e = 0; e < 4; e++) {
            unsigned int vj = vjtab[(f + 3) * 16 + hq * 4 + e];
            const unsigned short* vp = &vb[(size_t)vj * 128 + ch0 + m];
            vA1[f][e] = vp[0];
            vB1[f][e] = vp[16];
        }
    }

    // ---- PV: O^T = V^T . P^T, A-fragments from registers ----
    ffrag acc0 = ffrag{0,0,0,0};
    ffrag acc1 = ffrag{0,0,0,0};
    #pragma unroll
    for (int f = 0; f < 3; f++) {
        u32x2 pb; pb.x = cvtpk(s[f][0], s[f][1]); pb.y = cvtpk(s[f][2], s[f][3]);
        u32x2 av0, av1;
        av0.x = (unsigned)vA0[f][0] | ((unsigned)vA0[f][1] << 16);
        av0.y = (unsigned)vA0[f][2] | ((unsigned)vA0[f][3] << 16);
        av1.x = (unsigned)vB0[f][0] | ((unsigned)vB0[f][1] << 16);
        av1.y = (unsigned)vB0[f][2] | ((unsigned)vB0[f][3] << 16);
        asm("v_mfma_f32_16x16x16_bf16 %0, %1, %2, %0" : "+v"(acc0) : "v"(av0), "v"(pb));
        asm("v_mfma_f32_16x16x16_bf16 %0, %1, %2, %0" : "+v"(acc1) : "v"(av1), "v"(pb));
    }
    #pragma unroll
    for (int f = 0; f < 3; f++) {
        u32x2 pb; pb.x = cvtpk(s[f + 3][0], s[f + 3][1]); pb.y = cvtpk(s[f + 3][2], s[f + 3][3]);
        u32x2 av0, av1;
        av0.x = (unsigned)vA1[f][0] | ((unsigned)vA1[f][1] << 16);
        av0.y = (unsigned)vA1[f][2] | ((unsigned)vA1[f][3] << 16);
        av1.x = (unsigned)vB1[f][0] | ((unsigned)vB1[f][1] << 16);
        av1.y = (unsigned)vB1[f][2] | ((unsigned)vB1[f][3] << 16);
        asm("v_mfma_f32_16x16x16_bf16 %0, %1, %2, %0" : "+v"(acc0) : "v"(av0), "v"(pb));
        asm("v_mfma_f32_16x16x16_bf16 %0, %1, %2, %0" : "+v"(acc1) : "v"(av1), "v"(pb));
    }

    // ---- epilogue: scale by 1/sum, pack bf16, store O[vox][ch] ----
    size_t obase = (size_t)vox * 128 + ch0 + hq * 4;
    {
        u32x2 ov;
        ov.x = cvtpk(acc0[0] * inv, acc0[1] * inv);
        ov.y = cvtpk(acc0[2] * inv, acc0[3] * inv);
        *(u32x2*)&ob[obase] = ov;
    }
    {
        u32x2 ov;
        ov.x = cvtpk(acc1[0] * inv, acc1[1] * inv);
        ov.y = cvtpk(acc1[2] * inv, acc1[3] * inv);
        *(u32x2*)&ob[obase + 16] = ov;
    }
}

// -------- Kernel 3: proj GEMM + bias + residual + transpose to (C, N) --------
__global__ __launch_bounds__(256) void proj_gemm(const unsigned short* __restrict__ a,
                                                 const unsigned short* __restrict__ wp,
                                                 const float* __restrict__ bias,
                                                 const float* __restrict__ xres,
                                                 float* __restrict__ out) {
    __shared__ __align__(16) unsigned short a_s[64 * 136];
    __shared__ __align__(16) unsigned short b_s[64 * 136];
    int t = threadIdx.x;
    int m0 = blockIdx.x * 64, o0 = blockIdx.y * 64;
    {
        int r4 = t >> 4, c8 = t & 15;
        #pragma unroll
        for (int pass = 0; pass < 4; pass++) {
            int r = pass * 16 + r4;
            *(uint4*)&a_s[r * 136 + c8 * 8] =
                *(const uint4*)&a[(size_t)(m0 + r) * 128 + c8 * 8];
            *(uint4*)&b_s[r * 136 + c8 * 8] =
                *(const uint4*)&wp[(size_t)(o0 + r) * 128 + c8 * 8];
        }
    }
    __syncthreads();
    int wvi = t >> 6, lane = t & 63, m = lane & 15, quad = lane >> 4;
    ffrag acc[4] = {ffrag{0,0,0,0}, ffrag{0,0,0,0}, ffrag{0,0,0,0}, ffrag{0,0,0,0}};
    #pragma unroll
    for (int kk = 0; kk < 4; kk++) {
        bfrag av = *(bfrag*)&a_s[(wvi * 16 + m) * 136 + kk * 32 + quad * 8];
        #pragma unroll
        for (int nt = 0; nt < 4; nt++) {
            bfrag bb = *(bfrag*)&b_s[(nt * 16 + m) * 136 + kk * 32 + quad * 8];
            acc[nt] = __builtin_amdgcn_mfma_f32_16x16x32_bf16(av, bb, acc[nt], 0, 0, 0);
        }
    }
    #pragma unroll
    for (int nt = 0; nt < 4; nt++) {
        int o = o0 + nt * 16 + m;
        float bs = bias[o];
        int vg = m0 + wvi * 16 + quad * 4;
        float4 r = *(const float4*)&xres[(size_t)o * N_VOX + vg];
        float4 ov;
        ov.x = acc[nt][0] + bs + r.x;
        ov.y = acc[nt][1] + bs + r.y;
        ov.z = acc[nt][2] + bs + r.z;
        ov.w = acc[nt][3] + bs + r.w;
        *(float4*)&out[(size_t)o * N_VOX + vg] = ov;
    }
}

extern "C" void kernel_launch(void* const* d_in, const int* in_sizes, int n_in,
                              void* d_out, int out_size, void* d_ws, size_t ws_size,
                              hipStream_t stream) {
    const float* x      = (const float*)d_in[0];
    const float* gamma  = (const float*)d_in[1];
    const float* beta   = (const float*)d_in[2];
    const float* qkv_w  = (const float*)d_in[3];
    const float* qkv_b  = (const float*)d_in[4];
    const float* proj_w = (const float*)d_in[5];
    const float* proj_b = (const float*)d_in[6];
    float* out = (float*)d_out;

    unsigned short* qkv  = (unsigned short*)d_ws;                            // 24 MB
    unsigned short* attn = (unsigned short*)((char*)d_ws + (24u << 20));     // 8 MB
    unsigned short* wq   = (unsigned short*)((char*)d_ws + (32u << 20));     // 96 KB
    unsigned short* wpb  = wq + 384 * 128;                                   // 32 KB

    hipLaunchKernelGGL(wconv, dim3(64), dim3(256), 0, stream, qkv_w, proj_w, wq, wpb);
    hipLaunchKernelGGL(ln_qkv, dim3(512), dim3(256), 0, stream,
                       x, gamma, beta, wq, qkv_b, qkv);
    const unsigned short* qb = qkv;
    const unsigned short* kb = qkv + (size_t)N_VOX * 128;
    const unsigned short* vb = qkv + (size_t)2 * N_VOX * 128;
    hipLaunchKernelGGL(attn_kernel, dim3(2048), dim3(256), 0, stream, qb, kb, vb, attn);
    hipLaunchKernelGGL(proj_gemm, dim3(512, 2), dim3(256), 0, stream, attn, wpb, proj_b, x, out);
}

// Round 16
// 112.893 us; speedup vs baseline: 1.0573x; 1.0573x over previous
//
#include <hip/hip_runtime.h>

#define N_VOX 32768
#define CCH 128
#define EPSV 1e-5f

typedef __attribute__((ext_vector_type(8))) short bfrag;
typedef __attribute__((ext_vector_type(4))) float ffrag;
typedef __attribute__((ext_vector_type(2))) unsigned int u32x2;

__device__ __forceinline__ unsigned short f2bf(float f) {
    union { float f; unsigned int i; } c; c.f = f;
    unsigned int i = c.i;
    return (unsigned short)((i + 0x7FFFu + ((i >> 16) & 1u)) >> 16);
}
__device__ __forceinline__ unsigned int cvtpk(float lo, float hi) {
    unsigned int r;
    asm("v_cvt_pk_bf16_f32 %0, %1, %2" : "=v"(r) : "v"(lo), "v"(hi));
    return r;
}

// -------- Kernel 0: one-shot fp32 -> bf16 weight conversion --------
__global__ __launch_bounds__(256) void wconv(const float* __restrict__ qkv_w,
                                             const float* __restrict__ proj_w,
                                             unsigned short* __restrict__ wq,
                                             unsigned short* __restrict__ wp) {
    int i = blockIdx.x * 256 + threadIdx.x;
    if (i < 12288) {
        float4 v = ((const float4*)qkv_w)[i];
        u32x2 o; o.x = cvtpk(v.x, v.y); o.y = cvtpk(v.z, v.w);
        *(u32x2*)&wq[i * 4] = o;
    } else {
        int j = i - 12288;
        float4 v = ((const float4*)proj_w)[j];
        u32x2 o; o.x = cvtpk(v.x, v.y); o.y = cvtpk(v.z, v.w);
        *(u32x2*)&wp[j * 4] = o;
    }
}

// -------- Kernel 1: fused LayerNorm + QKV GEMM (og=1, verified round-11) --------
__global__ __launch_bounds__(256) void ln_qkv(const float* __restrict__ x,
                                              const float* __restrict__ gamma,
                                              const float* __restrict__ beta,
                                              const unsigned short* __restrict__ wq,
                                              const float* __restrict__ bias,
                                              unsigned short* __restrict__ qkv) {
    __shared__ __align__(16) unsigned short a_s[64 * 136];
    __shared__ __align__(16) unsigned short b_s[64 * 136];
    __shared__ float ps[256], pq[256];
    __shared__ float muS[64], rsS[64];
    __shared__ float g[128], bta[128];
    int t = threadIdx.x;
    int v0 = blockIdx.x * 64;
    if (t < 128) { g[t] = gamma[t]; bta[t] = beta[t]; }
    int cq = t >> 6, v = t & 63;
    float xr[32];
    float s = 0.f, sq = 0.f;
    #pragma unroll
    for (int i = 0; i < 32; i++) {
        float val = x[(size_t)(cq * 32 + i) * N_VOX + v0 + v];
        xr[i] = val; s += val; sq += val * val;
    }
    ps[t] = s; pq[t] = sq;
    __syncthreads();
    if (t < 64) {
        float S = ps[t] + ps[t + 64] + ps[t + 128] + ps[t + 192];
        float Q = pq[t] + pq[t + 64] + pq[t + 128] + pq[t + 192];
        float mu = S * (1.0f / 128.0f);
        float var = Q * (1.0f / 128.0f) - mu * mu;
        muS[t] = mu; rsS[t] = rsqrtf(var + EPSV);
    }
    __syncthreads();
    {
        float mu = muS[v], rs = rsS[v];
        #pragma unroll
        for (int i8 = 0; i8 < 4; i8++) {
            float val[8];
            #pragma unroll
            for (int k = 0; k < 8; k++) {
                int c = cq * 32 + i8 * 8 + k;
                val[k] = (xr[i8 * 8 + k] - mu) * rs * g[c] + bta[c];
            }
            uint4 q;
            q.x = cvtpk(val[0], val[1]);
            q.y = cvtpk(val[2], val[3]);
            q.z = cvtpk(val[4], val[5]);
            q.w = cvtpk(val[6], val[7]);
            *(uint4*)&a_s[v * 136 + cq * 32 + i8 * 8] = q;
        }
    }
    __syncthreads();
    int lane = t & 63, wvi = t >> 6, m = lane & 15, quad = lane >> 4;
    bfrag areg[4];
    #pragma unroll
    for (int kk = 0; kk < 4; kk++)
        areg[kk] = *(bfrag*)&a_s[(wvi * 16 + m) * 136 + kk * 32 + quad * 8];
    for (int t0 = 0; t0 < 6; t0++) {
        int o0 = t0 * 64;
        {
            int r4 = t >> 4, c8 = t & 15;
            #pragma unroll
            for (int pass = 0; pass < 4; pass++) {
                int r = pass * 16 + r4;
                *(uint4*)&b_s[r * 136 + c8 * 8] =
                    *(const uint4*)&wq[(size_t)(o0 + r) * 128 + c8 * 8];
            }
        }
        __syncthreads();
        ffrag acc[4] = {ffrag{0,0,0,0}, ffrag{0,0,0,0}, ffrag{0,0,0,0}, ffrag{0,0,0,0}};
        #pragma unroll
        for (int kk = 0; kk < 4; kk++) {
            #pragma unroll
            for (int nt = 0; nt < 4; nt++) {
                bfrag bb = *(bfrag*)&b_s[(nt * 16 + m) * 136 + kk * 32 + quad * 8];
                acc[nt] = __builtin_amdgcn_mfma_f32_16x16x32_bf16(areg[kk], bb, acc[nt], 0, 0, 0);
            }
        }
        bool isq = (o0 < 128);
        #pragma unroll
        for (int nt = 0; nt < 4; nt++) {
            int o = o0 + nt * 16 + m;
            float bs = bias[o];
            int sec = o >> 7;
            int oc = o & 127;
            unsigned short* dst = qkv + (size_t)sec * ((size_t)N_VOX * 128);
            #pragma unroll
            for (int r = 0; r < 4; r++) {
                int vg = v0 + wvi * 16 + quad * 4 + r;
                float val = acc[nt][r] + bs;
                if (isq) val *= 0.17677669529663687f;
                dst[(size_t)vg * 128 + oc] = f2bf(val);
            }
        }
        __syncthreads();
    }
}

// -------- Kernel 2: neighborhood attention, 2x2x4 cubes (round-11) --------
// Verified round-11 kernel + T5: s_setprio(1) around the QK^T and PV MFMA
// clusters. Pure scheduler hint (no pressure/layout change): with 4+
// blocks/CU whose waves sit at different phases after the early barrier,
// the CU scheduler favors MFMA-issuing waves. (launch_bounds forcing and
// register prefetch are banned — both miscompile under pressure here.)
#define VT2 100
__global__ __launch_bounds__(256) void attn_kernel(const unsigned short* __restrict__ qb,
                                                   const unsigned short* __restrict__ kb,
                                                   const unsigned short* __restrict__ vb,
                                                   unsigned short* __restrict__ ob) {
    __shared__ unsigned int vjtab[96];                    // region idx -> voxel idx
    __shared__ __align__(16) unsigned int vmsk[96];       // region idx -> 16-bit voxel validity
    __shared__ __align__(16) unsigned short vt[4][32 * VT2];  // per-head V^T slice

    int t = threadIdx.x;
    int hw = blockIdx.x;
    int bidx = (hw & 7) * 256 + (hw >> 3);                // XCD swizzle
    int czi = bidx & 7, cyi = (bidx >> 3) & 15, cxi = bidx >> 7;
    int cx0 = cxi << 1, cy0 = cyi << 1, cz0 = czi << 2;
    int rx0 = min(max(cx0 - 1, 0), 28);
    int ry0 = min(max(cy0 - 1, 0), 28);
    int rz0 = min(max(cz0 - 1, 0), 26);

    if (t < 96) {
        int r = t;
        int ax = r / 24;
        int rem = r - ax * 24;
        int by = rem / 6;
        int cz = rem - by * 6;
        vjtab[t] = (unsigned)(((rx0 + ax) << 10) + ((ry0 + by) << 5) + (rz0 + cz));
        int wx0 = min(max(cx0 - 1, 0), 29) - rx0;
        int wx1 = min(cx0, 29) - rx0;
        int wy0 = min(max(cy0 - 1, 0), 29) - ry0;
        int wy1 = min(cy0, 29) - ry0;
        unsigned zn = 0;
        #pragma unroll
        for (int vz = 0; vz < 4; vz++) {
            int wz = min(max(cz0 + vz - 1, 0), 29) - rz0;
            if ((unsigned)(cz - wz) <= 2u) zn |= 1u << vz;
        }
        bool x0 = (unsigned)(ax - wx0) <= 2u;
        bool x1 = (unsigned)(ax - wx1) <= 2u;
        bool y0 = (unsigned)(by - wy0) <= 2u;
        bool y1 = (unsigned)(by - wy1) <= 2u;
        unsigned msk = 0;
        if (x0 && y0) msk |= zn;
        if (x0 && y1) msk |= zn << 4;
        if (x1 && y0) msk |= zn << 8;
        if (x1 && y1) msk |= zn << 12;
        vmsk[t] = msk;
    }
    __syncthreads();

    int wave = t >> 6, lane = t & 63;
    int hq = lane >> 4;
    int m = lane & 15;
    int ch0 = wave * 32;

    unsigned short* vts = &vt[wave][0];
    {
        const int cp = m;
        #pragma unroll
        for (int u = 0; u < 6; u++) {
            int rb = u * 16 + hq * 4;
            unsigned int j0 = vjtab[rb + 0];
            unsigned int j1 = vjtab[rb + 1];
            unsigned int j2 = vjtab[rb + 2];
            unsigned int j3 = vjtab[rb + 3];
            unsigned int d0 = *(const unsigned int*)&vb[(size_t)j0 * 128 + ch0 + cp * 2];
            unsigned int d1 = *(const unsigned int*)&vb[(size_t)j1 * 128 + ch0 + cp * 2];
            unsigned int d2 = *(const unsigned int*)&vb[(size_t)j2 * 128 + ch0 + cp * 2];
            unsigned int d3 = *(const unsigned int*)&vb[(size_t)j3 * 128 + ch0 + cp * 2];
            unsigned int lo01 = __builtin_amdgcn_perm(d1, d0, 0x05040100u);
            unsigned int lo23 = __builtin_amdgcn_perm(d3, d2, 0x05040100u);
            unsigned int hi01 = __builtin_amdgcn_perm(d1, d0, 0x07060302u);
            unsigned int hi23 = __builtin_amdgcn_perm(d3, d2, 0x07060302u);
            u32x2 wlo; wlo.x = lo01; wlo.y = lo23;
            u32x2 whi; whi.x = hi01; whi.y = hi23;
            *(u32x2*)&vts[(2 * cp) * VT2 + rb] = wlo;
            *(u32x2*)&vts[(2 * cp + 1) * VT2 + rb] = whi;
        }
    }

    int gx = cx0 + (m >> 3), gy = cy0 + ((m >> 2) & 1), gz = cz0 + (m & 3);
    int vox = (gx << 10) + (gy << 5) + gz;

    bfrag qf = *(const bfrag*)&qb[(size_t)vox * 128 + ch0 + hq * 8];
    ffrag s[6];
    __builtin_amdgcn_s_setprio(1);
    #pragma unroll
    for (int f = 0; f < 6; f++) {
        unsigned int vj = vjtab[f * 16 + m];
        bfrag kf = *(const bfrag*)&kb[(size_t)vj * 128 + ch0 + hq * 8];
        s[f] = __builtin_amdgcn_mfma_f32_16x16x32_bf16(kf, qf, ffrag{0,0,0,0}, 0, 0, 0);
    }
    __builtin_amdgcn_s_setprio(0);

    float mx = -1e30f;
    #pragma unroll
    for (int f = 0; f < 6; f++) {
        uint4 mk = *(const uint4*)&vmsk[f * 16 + hq * 4];
        unsigned mm[4] = {mk.x, mk.y, mk.z, mk.w};
        #pragma unroll
        for (int i = 0; i < 4; i++) {
            bool valid = (mm[i] >> m) & 1u;
            float sv = valid ? s[f][i] : -1e30f;
            s[f][i] = sv;
            mx = fmaxf(mx, sv);
        }
    }
    mx = fmaxf(mx, __shfl_xor(mx, 16));
    mx = fmaxf(mx, __shfl_xor(mx, 32));
    float sum = 0.f;
    #pragma unroll
    for (int f = 0; f < 6; f++) {
        #pragma unroll
        for (int i = 0; i < 4; i++) {
            float p = __expf(s[f][i] - mx);
            s[f][i] = p;
            sum += p;
        }
    }
    sum += __shfl_xor(sum, 16);
    sum += __shfl_xor(sum, 32);
    float inv = 1.0f / sum;

    ffrag acc0 = ffrag{0,0,0,0};
    ffrag acc1 = ffrag{0,0,0,0};
    const unsigned short* ab = &vt[wave][m * VT2 + hq * 4];
    __builtin_amdgcn_s_setprio(1);
    #pragma unroll
    for (int f = 0; f < 6; f++) {
        u32x2 pb; pb.x = cvtpk(s[f][0], s[f][1]); pb.y = cvtpk(s[f][2], s[f][3]);
        u32x2 av0 = *(const u32x2*)&ab[f * 16];
        u32x2 av1 = *(const u32x2*)&ab[16 * VT2 + f * 16];
        asm("v_mfma_f32_16x16x16_bf16 %0, %1, %2, %0" : "+v"(acc0) : "v"(av0), "v"(pb));
        asm("v_mfma_f32_16x16x16_bf16 %0, %1, %2, %0" : "+v"(acc1) : "v"(av1), "v"(pb));
    }
    __builtin_amdgcn_s_setprio(0);

    size_t obase = (size_t)vox * 128 + ch0 + hq * 4;
    {
        u32x2 ov;
        ov.x = cvtpk(acc0[0] * inv, acc0[1] * inv);
        ov.y = cvtpk(acc0[2] * inv, acc0[3] * inv);
        *(u32x2*)&ob[obase] = ov;
    }
    {
        u32x2 ov;
        ov.x = cvtpk(acc1[0] * inv, acc1[1] * inv);
        ov.y = cvtpk(acc1[2] * inv, acc1[3] * inv);
        *(u32x2*)&ob[obase + 16] = ov;
    }
}

// -------- Kernel 3: proj GEMM + bias + residual + transpose to (C, N) --------
__global__ __launch_bounds__(256) void proj_gemm(const unsigned short* __restrict__ a,
                                                 const unsigned short* __restrict__ wp,
                                                 const float* __restrict__ bias,
                                                 const float* __restrict__ xres,
                                                 float* __restrict__ out) {
    __shared__ __align__(16) unsigned short a_s[64 * 136];
    __shared__ __align__(16) unsigned short b_s[64 * 136];
    int t = threadIdx.x;
    int m0 = blockIdx.x * 64, o0 = blockIdx.y * 64;
    {
        int r4 = t >> 4, c8 = t & 15;
        #pragma unroll
        for (int pass = 0; pass < 4; pass++) {
            int r = pass * 16 + r4;
            *(uint4*)&a_s[r * 136 + c8 * 8] =
                *(const uint4*)&a[(size_t)(m0 + r) * 128 + c8 * 8];
            *(uint4*)&b_s[r * 136 + c8 * 8] =
                *(const uint4*)&wp[(size_t)(o0 + r) * 128 + c8 * 8];
        }
    }
    __syncthreads();
    int wvi = t >> 6, lane = t & 63, m = lane & 15, quad = lane >> 4;
    ffrag acc[4] = {ffrag{0,0,0,0}, ffrag{0,0,0,0}, ffrag{0,0,0,0}, ffrag{0,0,0,0}};
    #pragma unroll
    for (int kk = 0; kk < 4; kk++) {
        bfrag av = *(bfrag*)&a_s[(wvi * 16 + m) * 136 + kk * 32 + quad * 8];
        #pragma unroll
        for (int nt = 0; nt < 4; nt++) {
            bfrag bb = *(bfrag*)&b_s[(nt * 16 + m) * 136 + kk * 32 + quad * 8];
            acc[nt] = __builtin_amdgcn_mfma_f32_16x16x32_bf16(av, bb, acc[nt], 0, 0, 0);
        }
    }
    #pragma unroll
    for (int nt = 0; nt < 4; nt++) {
        int o = o0 + nt * 16 + m;
        float bs = bias[o];
        int vg = m0 + wvi * 16 + quad * 4;
        float4 r = *(const float4*)&xres[(size_t)o * N_VOX + vg];
        float4 ov;
        ov.x = acc[nt][0] + bs + r.x;
        ov.y = acc[nt][1] + bs + r.y;
        ov.z = acc[nt][2] + bs + r.z;
        ov.w = acc[nt][3] + bs + r.w;
        *(float4*)&out[(size_t)o * N_VOX + vg] = ov;
    }
}

extern "C" void kernel_launch(void* const* d_in, const int* in_sizes, int n_in,
                              void* d_out, int out_size, void* d_ws, size_t ws_size,
                              hipStream_t stream) {
    const float* x      = (const float*)d_in[0];
    const float* gamma  = (const float*)d_in[1];
    const float* beta   = (const float*)d_in[2];
    const float* qkv_w  = (const float*)d_in[3];
    const float* qkv_b  = (const float*)d_in[4];
    const float* proj_w = (const float*)d_in[5];
    const float* proj_b = (const float*)d_in[6];
    float* out = (float*)d_out;

    unsigned short* qkv  = (unsigned short*)d_ws;                            // 24 MB
    unsigned short* attn = (unsigned short*)((char*)d_ws + (24u << 20));     // 8 MB
    unsigned short* wq   = (unsigned short*)((char*)d_ws + (32u << 20));     // 96 KB
    unsigned short* wpb  = wq + 384 * 128;                                   // 32 KB

    hipLaunchKernelGGL(wconv, dim3(64), dim3(256), 0, stream, qkv_w, proj_w, wq, wpb);
    hipLaunchKernelGGL(ln_qkv, dim3(512), dim3(256), 0, stream,
                       x, gamma, beta, wq, qkv_b, qkv);
    const unsigned short* qb = qkv;
    const unsigned short* kb = qkv + (size_t)N_VOX * 128;
    const unsigned short* vb = qkv + (size_t)2 * N_VOX * 128;
    hipLaunchKernelGGL(attn_kernel, dim3(2048), dim3(256), 0, stream, qb, kb, vb, attn);
    hipLaunchKernelGGL(proj_gemm, dim3(512, 2), dim3(256), 0, stream, attn, wpb, proj_b, x, out);
}

// Round 17
// 111.157 us; speedup vs baseline: 1.0738x; 1.0156x over previous
//
#include <hip/hip_runtime.h>

#define N_VOX 32768
#define CCH 128
#define EPSV 1e-5f

typedef __attribute__((ext_vector_type(8))) short bfrag;
typedef __attribute__((ext_vector_type(4))) float ffrag;
typedef __attribute__((ext_vector_type(2))) unsigned int u32x2;

__device__ __forceinline__ unsigned short f2bf(float f) {
    union { float f; unsigned int i; } c; c.f = f;
    unsigned int i = c.i;
    return (unsigned short)((i + 0x7FFFu + ((i >> 16) & 1u)) >> 16);
}
__device__ __forceinline__ unsigned int cvtpk(float lo, float hi) {
    unsigned int r;
    asm("v_cvt_pk_bf16_f32 %0, %1, %2" : "=v"(r) : "v"(lo), "v"(hi));
    return r;
}

// -------- Kernel 0: one-shot fp32 -> bf16 weight conversion --------
__global__ __launch_bounds__(256) void wconv(const float* __restrict__ qkv_w,
                                             const float* __restrict__ proj_w,
                                             unsigned short* __restrict__ wq,
                                             unsigned short* __restrict__ wp) {
    int i = blockIdx.x * 256 + threadIdx.x;
    if (i < 12288) {
        float4 v = ((const float4*)qkv_w)[i];
        u32x2 o; o.x = cvtpk(v.x, v.y); o.y = cvtpk(v.z, v.w);
        *(u32x2*)&wq[i * 4] = o;
    } else {
        int j = i - 12288;
        float4 v = ((const float4*)proj_w)[j];
        u32x2 o; o.x = cvtpk(v.x, v.y); o.y = cvtpk(v.z, v.w);
        *(u32x2*)&wp[j * 4] = o;
    }
}

// -------- Kernel 1: fused LayerNorm + QKV GEMM (og=1, verified round-11) --------
__global__ __launch_bounds__(256) void ln_qkv(const float* __restrict__ x,
                                              const float* __restrict__ gamma,
                                              const float* __restrict__ beta,
                                              const unsigned short* __restrict__ wq,
                                              const float* __restrict__ bias,
                                              unsigned short* __restrict__ qkv) {
    __shared__ __align__(16) unsigned short a_s[64 * 136];
    __shared__ __align__(16) unsigned short b_s[64 * 136];
    __shared__ float ps[256], pq[256];
    __shared__ float muS[64], rsS[64];
    __shared__ float g[128], bta[128];
    int t = threadIdx.x;
    int v0 = blockIdx.x * 64;
    if (t < 128) { g[t] = gamma[t]; bta[t] = beta[t]; }
    int cq = t >> 6, v = t & 63;
    float xr[32];
    float s = 0.f, sq = 0.f;
    #pragma unroll
    for (int i = 0; i < 32; i++) {
        float val = x[(size_t)(cq * 32 + i) * N_VOX + v0 + v];
        xr[i] = val; s += val; sq += val * val;
    }
    ps[t] = s; pq[t] = sq;
    __syncthreads();
    if (t < 64) {
        float S = ps[t] + ps[t + 64] + ps[t + 128] + ps[t + 192];
        float Q = pq[t] + pq[t + 64] + pq[t + 128] + pq[t + 192];
        float mu = S * (1.0f / 128.0f);
        float var = Q * (1.0f / 128.0f) - mu * mu;
        muS[t] = mu; rsS[t] = rsqrtf(var + EPSV);
    }
    __syncthreads();
    {
        float mu = muS[v], rs = rsS[v];
        #pragma unroll
        for (int i8 = 0; i8 < 4; i8++) {
            float val[8];
            #pragma unroll
            for (int k = 0; k < 8; k++) {
                int c = cq * 32 + i8 * 8 + k;
                val[k] = (xr[i8 * 8 + k] - mu) * rs * g[c] + bta[c];
            }
            uint4 q;
            q.x = cvtpk(val[0], val[1]);
            q.y = cvtpk(val[2], val[3]);
            q.z = cvtpk(val[4], val[5]);
            q.w = cvtpk(val[6], val[7]);
            *(uint4*)&a_s[v * 136 + cq * 32 + i8 * 8] = q;
        }
    }
    __syncthreads();
    int lane = t & 63, wvi = t >> 6, m = lane & 15, quad = lane >> 4;
    bfrag areg[4];
    #pragma unroll
    for (int kk = 0; kk < 4; kk++)
        areg[kk] = *(bfrag*)&a_s[(wvi * 16 + m) * 136 + kk * 32 + quad * 8];
    for (int t0 = 0; t0 < 6; t0++) {
        int o0 = t0 * 64;
        {
            int r4 = t >> 4, c8 = t & 15;
            #pragma unroll
            for (int pass = 0; pass < 4; pass++) {
                int r = pass * 16 + r4;
                *(uint4*)&b_s[r * 136 + c8 * 8] =
                    *(const uint4*)&wq[(size_t)(o0 + r) * 128 + c8 * 8];
            }
        }
        __syncthreads();
        ffrag acc[4] = {ffrag{0,0,0,0}, ffrag{0,0,0,0}, ffrag{0,0,0,0}, ffrag{0,0,0,0}};
        #pragma unroll
        for (int kk = 0; kk < 4; kk++) {
            #pragma unroll
            for (int nt = 0; nt < 4; nt++) {
                bfrag bb = *(bfrag*)&b_s[(nt * 16 + m) * 136 + kk * 32 + quad * 8];
                acc[nt] = __builtin_amdgcn_mfma_f32_16x16x32_bf16(areg[kk], bb, acc[nt], 0, 0, 0);
            }
        }
        bool isq = (o0 < 128);
        #pragma unroll
        for (int nt = 0; nt < 4; nt++) {
            int o = o0 + nt * 16 + m;
            float bs = bias[o];
            int sec = o >> 7;
            int oc = o & 127;
            unsigned short* dst = qkv + (size_t)sec * ((size_t)N_VOX * 128);
            #pragma unroll
            for (int r = 0; r < 4; r++) {
                int vg = v0 + wvi * 16 + quad * 4 + r;
                float val = acc[nt][r] + bs;
                if (isq) val *= 0.17677669529663687f;
                dst[(size_t)vg * 128 + oc] = f2bf(val);
            }
        }
        __syncthreads();
    }
}

// -------- Kernel 2: neighborhood attention via MFMA, 2x2x4-cube tiling --------
// Verified round-11 kernel, byte-identical.
#define VT2 100
__global__ __launch_bounds__(256) void attn_kernel(const unsigned short* __restrict__ qb,
                                                   const unsigned short* __restrict__ kb,
                                                   const unsigned short* __restrict__ vb,
                                                   unsigned short* __restrict__ ob) {
    __shared__ unsigned int vjtab[96];                    // region idx -> voxel idx
    __shared__ __align__(16) unsigned int vmsk[96];       // region idx -> 16-bit voxel validity
    __shared__ __align__(16) unsigned short vt[4][32 * VT2];  // per-head V^T slice

    int t = threadIdx.x;
    int hw = blockIdx.x;
    int bidx = (hw & 7) * 256 + (hw >> 3);                // XCD swizzle
    int czi = bidx & 7, cyi = (bidx >> 3) & 15, cxi = bidx >> 7;
    int cx0 = cxi << 1, cy0 = cyi << 1, cz0 = czi << 2;
    int rx0 = min(max(cx0 - 1, 0), 28);
    int ry0 = min(max(cy0 - 1, 0), 28);
    int rz0 = min(max(cz0 - 1, 0), 26);

    if (t < 96) {
        int r = t;
        int ax = r / 24;
        int rem = r - ax * 24;
        int by = rem / 6;
        int cz = rem - by * 6;
        vjtab[t] = (unsigned)(((rx0 + ax) << 10) + ((ry0 + by) << 5) + (rz0 + cz));
        int wx0 = min(max(cx0 - 1, 0), 29) - rx0;
        int wx1 = min(cx0, 29) - rx0;
        int wy0 = min(max(cy0 - 1, 0), 29) - ry0;
        int wy1 = min(cy0, 29) - ry0;
        unsigned zn = 0;
        #pragma unroll
        for (int vz = 0; vz < 4; vz++) {
            int wz = min(max(cz0 + vz - 1, 0), 29) - rz0;
            if ((unsigned)(cz - wz) <= 2u) zn |= 1u << vz;
        }
        bool x0 = (unsigned)(ax - wx0) <= 2u;
        bool x1 = (unsigned)(ax - wx1) <= 2u;
        bool y0 = (unsigned)(by - wy0) <= 2u;
        bool y1 = (unsigned)(by - wy1) <= 2u;
        unsigned msk = 0;
        if (x0 && y0) msk |= zn;
        if (x0 && y1) msk |= zn << 4;
        if (x1 && y0) msk |= zn << 8;
        if (x1 && y1) msk |= zn << 12;
        vmsk[t] = msk;
    }
    __syncthreads();

    int wave = t >> 6, lane = t & 63;
    int hq = lane >> 4;
    int m = lane & 15;
    int ch0 = wave * 32;

    unsigned short* vts = &vt[wave][0];
    {
        const int cp = m;
        #pragma unroll
        for (int u = 0; u < 6; u++) {
            int rb = u * 16 + hq * 4;
            unsigned int j0 = vjtab[rb + 0];
            unsigned int j1 = vjtab[rb + 1];
            unsigned int j2 = vjtab[rb + 2];
            unsigned int j3 = vjtab[rb + 3];
            unsigned int d0 = *(const unsigned int*)&vb[(size_t)j0 * 128 + ch0 + cp * 2];
            unsigned int d1 = *(const unsigned int*)&vb[(size_t)j1 * 128 + ch0 + cp * 2];
            unsigned int d2 = *(const unsigned int*)&vb[(size_t)j2 * 128 + ch0 + cp * 2];
            unsigned int d3 = *(const unsigned int*)&vb[(size_t)j3 * 128 + ch0 + cp * 2];
            unsigned int lo01 = __builtin_amdgcn_perm(d1, d0, 0x05040100u);
            unsigned int lo23 = __builtin_amdgcn_perm(d3, d2, 0x05040100u);
            unsigned int hi01 = __builtin_amdgcn_perm(d1, d0, 0x07060302u);
            unsigned int hi23 = __builtin_amdgcn_perm(d3, d2, 0x07060302u);
            u32x2 wlo; wlo.x = lo01; wlo.y = lo23;
            u32x2 whi; whi.x = hi01; whi.y = hi23;
            *(u32x2*)&vts[(2 * cp) * VT2 + rb] = wlo;
            *(u32x2*)&vts[(2 * cp + 1) * VT2 + rb] = whi;
        }
    }

    int gx = cx0 + (m >> 3), gy = cy0 + ((m >> 2) & 1), gz = cz0 + (m & 3);
    int vox = (gx << 10) + (gy << 5) + gz;

    bfrag qf = *(const bfrag*)&qb[(size_t)vox * 128 + ch0 + hq * 8];
    ffrag s[6];
    #pragma unroll
    for (int f = 0; f < 6; f++) {
        unsigned int vj = vjtab[f * 16 + m];
        bfrag kf = *(const bfrag*)&kb[(size_t)vj * 128 + ch0 + hq * 8];
        s[f] = __builtin_amdgcn_mfma_f32_16x16x32_bf16(kf, qf, ffrag{0,0,0,0}, 0, 0, 0);
    }

    float mx = -1e30f;
    #pragma unroll
    for (int f = 0; f < 6; f++) {
        uint4 mk = *(const uint4*)&vmsk[f * 16 + hq * 4];
        unsigned mm[4] = {mk.x, mk.y, mk.z, mk.w};
        #pragma unroll
        for (int i = 0; i < 4; i++) {
            bool valid = (mm[i] >> m) & 1u;
            float sv = valid ? s[f][i] : -1e30f;
            s[f][i] = sv;
            mx = fmaxf(mx, sv);
        }
    }
    mx = fmaxf(mx, __shfl_xor(mx, 16));
    mx = fmaxf(mx, __shfl_xor(mx, 32));
    float sum = 0.f;
    #pragma unroll
    for (int f = 0; f < 6; f++) {
        #pragma unroll
        for (int i = 0; i < 4; i++) {
            float p = __expf(s[f][i] - mx);
            s[f][i] = p;
            sum += p;
        }
    }
    sum += __shfl_xor(sum, 16);
    sum += __shfl_xor(sum, 32);
    float inv = 1.0f / sum;

    ffrag acc0 = ffrag{0,0,0,0};
    ffrag acc1 = ffrag{0,0,0,0};
    const unsigned short* ab = &vt[wave][m * VT2 + hq * 4];
    #pragma unroll
    for (int f = 0; f < 6; f++) {
        u32x2 pb; pb.x = cvtpk(s[f][0], s[f][1]); pb.y = cvtpk(s[f][2], s[f][3]);
        u32x2 av0 = *(const u32x2*)&ab[f * 16];
        u32x2 av1 = *(const u32x2*)&ab[16 * VT2 + f * 16];
        asm("v_mfma_f32_16x16x16_bf16 %0, %1, %2, %0" : "+v"(acc0) : "v"(av0), "v"(pb));
        asm("v_mfma_f32_16x16x16_bf16 %0, %1, %2, %0" : "+v"(acc1) : "v"(av1), "v"(pb));
    }

    size_t obase = (size_t)vox * 128 + ch0 + hq * 4;
    {
        u32x2 ov;
        ov.x = cvtpk(acc0[0] * inv, acc0[1] * inv);
        ov.y = cvtpk(acc0[2] * inv, acc0[3] * inv);
        *(u32x2*)&ob[obase] = ov;
    }
    {
        u32x2 ov;
        ov.x = cvtpk(acc1[0] * inv, acc1[1] * inv);
        ov.y = cvtpk(acc1[2] * inv, acc1[3] * inv);
        *(u32x2*)&ob[obase + 16] = ov;
    }
}

// -------- Kernel 3: proj GEMM + bias + residual + transpose to (C, N) --------
__global__ __launch_bounds__(256) void proj_gemm(const unsigned short* __restrict__ a,
                                                 const unsigned short* __restrict__ wp,
                                                 const float* __restrict__ bias,
                                                 const float* __restrict__ xres,
                                                 float* __restrict__ out) {
    __shared__ __align__(16) unsigned short a_s[64 * 136];
    __shared__ __align__(16) unsigned short b_s[64 * 136];
    int t = threadIdx.x;
    int m0 = blockIdx.x * 64, o0 = blockIdx.y * 64;
    {
        int r4 = t >> 4, c8 = t & 15;
        #pragma unroll
        for (int pass = 0; pass < 4; pass++) {
            int r = pass * 16 + r4;
            *(uint4*)&a_s[r * 136 + c8 * 8] =
                *(const uint4*)&a[(size_t)(m0 + r) * 128 + c8 * 8];
            *(uint4*)&b_s[r * 136 + c8 * 8] =
                *(const uint4*)&wp[(size_t)(o0 + r) * 128 + c8 * 8];
        }
    }
    __syncthreads();
    int wvi = t >> 6, lane = t & 63, m = lane & 15, quad = lane >> 4;
    ffrag acc[4] = {ffrag{0,0,0,0}, ffrag{0,0,0,0}, ffrag{0,0,0,0}, ffrag{0,0,0,0}};
    #pragma unroll
    for (int kk = 0; kk < 4; kk++) {
        bfrag av = *(bfrag*)&a_s[(wvi * 16 + m) * 136 + kk * 32 + quad * 8];
        #pragma unroll
        for (int nt = 0; nt < 4; nt++) {
            bfrag bb = *(bfrag*)&b_s[(nt * 16 + m) * 136 + kk * 32 + quad * 8];
            acc[nt] = __builtin_amdgcn_mfma_f32_16x16x32_bf16(av, bb, acc[nt], 0, 0, 0);
        }
    }
    #pragma unroll
    for (int nt = 0; nt < 4; nt++) {
        int o = o0 + nt * 16 + m;
        float bs = bias[o];
        int vg = m0 + wvi * 16 + quad * 4;
        float4 r = *(const float4*)&xres[(size_t)o * N_VOX + vg];
        float4 ov;
        ov.x = acc[nt][0] + bs + r.x;
        ov.y = acc[nt][1] + bs + r.y;
        ov.z = acc[nt][2] + bs + r.z;
        ov.w = acc[nt][3] + bs + r.w;
        *(float4*)&out[(size_t)o * N_VOX + vg] = ov;
    }
}

extern "C" void kernel_launch(void* const* d_in, const int* in_sizes, int n_in,
                              void* d_out, int out_size, void* d_ws, size_t ws_size,
                              hipStream_t stream) {
    const float* x      = (const float*)d_in[0];
    const float* gamma  = (const float*)d_in[1];
    const float* beta   = (const float*)d_in[2];
    const float* qkv_w  = (const float*)d_in[3];
    const float* qkv_b  = (const float*)d_in[4];
    const float* proj_w = (const float*)d_in[5];
    const float* proj_b = (const float*)d_in[6];
    float* out = (float*)d_out;

    unsigned short* qkv  = (unsigned short*)d_ws;                            // 24 MB
    unsigned short* attn = (unsigned short*)((char*)d_ws + (24u << 20));     // 8 MB
    unsigned short* wq   = (unsigned short*)((char*)d_ws + (32u << 20));     // 96 KB
    unsigned short* wpb  = wq + 384 * 128;                                   // 32 KB

    hipLaunchKernelGGL(wconv, dim3(64), dim3(256), 0, stream, qkv_w, proj_w, wq, wpb);
    hipLaunchKernelGGL(ln_qkv, dim3(512), dim3(256), 0, stream,
                       x, gamma, beta, wq, qkv_b, qkv);
    const unsigned short* qb = qkv;
    const unsigned short* kb = qkv + (size_t)N_VOX * 128;
    const unsigned short* vb = qkv + (size_t)2 * N_VOX * 128;
    hipLaunchKernelGGL(attn_kernel, dim3(2048), dim3(256), 0, stream, qb, kb, vb, attn);
    hipLaunchKernelGGL(proj_gemm, dim3(512, 2), dim3(256), 0, stream, attn, wpb, proj_b, x, out);
}